// Round 5
// baseline (479.979 us; speedup 1.0000x reference)
//
#include <hip/hip_runtime.h>
#include <hip/hip_bf16.h>

#define NN 1024
#define IN_CH 128
#define EDGE_CH 32
#define OUT_CH 128

typedef __attribute__((ext_vector_type(8))) short bf16x8;
typedef __attribute__((ext_vector_type(4))) float f32x4;

// round-to-nearest-even float -> bf16
static __device__ __forceinline__ short f2bf(float f) {
    union { float f; unsigned u; } v; v.f = f;
    unsigned r = v.u + 0x7FFFu + ((v.u >> 16) & 1u);
    return (short)(r >> 16);
}

// async global->LDS DMA, 16 B per lane. gptr is per-lane; lptr is the
// wave-uniform LDS base (HW writes lane i at lptr + i*16).
static __device__ __forceinline__ void async_copy16(const float* gptr, float* lptr) {
    __builtin_amdgcn_global_load_lds(
        (const __attribute__((address_space(1))) void*)gptr,
        (__attribute__((address_space(3))) void*)lptr,
        16, 0, 0);
}

// ---------------------------------------------------------------------------
// Kernel A: PT[o][m] (bf16) = (node_mat @ node_weight)^T ; R = node_mat @ root
// ---------------------------------------------------------------------------
__global__ void node_gemm_kernel(const float* __restrict__ node_mat,
                                 const float* __restrict__ node_weight,
                                 const float* __restrict__ root,
                                 short* __restrict__ PT,
                                 float* __restrict__ R) {
    __shared__ float nm[2 * IN_CH];
    int tid = threadIdx.x;
    int n0 = blockIdx.x * 2;
    nm[tid] = node_mat[n0 * IN_CH + tid];
    __syncthreads();
    int o = tid & 127;
    int h = tid >> 7;
    const float* nr = &nm[h * IN_CH];
    float accp = 0.f, accr = 0.f;
#pragma unroll 8
    for (int c = 0; c < IN_CH; ++c) {
        float x = nr[c];
        accp += x * node_weight[c * OUT_CH + o];
        accr += x * root[c * OUT_CH + o];
    }
    R[(size_t)(n0 + h) * OUT_CH + o] = accr;
    PT[(size_t)o * NN + (n0 + h)] = f2bf(accp);
}

// ---------------------------------------------------------------------------
// Kernel B: out = adj @ P + R + bias.  Exclusive 16n x 16o tiles, grid 512,
// K=1024 split over 4 waves, LDS reduce. No atomics.
// A-frag: A[row=col][k=quad*8+j]; B-frag: B[k=quad*8+j][col]; D: row=quad*4+r.
// ---------------------------------------------------------------------------
__global__ void adjp_kernel(const float* __restrict__ adj,
                            const short* __restrict__ PT,
                            const float* __restrict__ R,
                            const float* __restrict__ bias,
                            float* __restrict__ out) {
    int nt = blockIdx.x >> 3;
    int ob = (blockIdx.x & 7) * 16;
    int tid = threadIdx.x;
    int wave = tid >> 6;
    int lane = tid & 63;
    int quad = lane >> 4;
    int col  = lane & 15;
    int n0 = nt * 16;

    f32x4 acc = {0.f, 0.f, 0.f, 0.f};
#pragma unroll 2
    for (int ks = 0; ks < 8; ++ks) {
        int k = wave * 256 + ks * 32 + quad * 8;
        const float* ap = adj + (size_t)(n0 + col) * NN + k;
        bf16x8 a;
#pragma unroll
        for (int j = 0; j < 8; ++j) a[j] = f2bf(ap[j]);
        bf16x8 b = *(const bf16x8*)(PT + (size_t)(ob + col) * NN + k);
        acc = __builtin_amdgcn_mfma_f32_16x16x32_bf16(a, b, acc, 0, 0, 0);
    }

    __shared__ float red[4][16][17];   // [wave][o_local][n_local], padded
#pragma unroll
    for (int r = 0; r < 4; ++r)
        red[wave][col][quad * 4 + r] = acc[r];
    __syncthreads();
    int ol = tid >> 4, nl = tid & 15;   // 256 threads = 16o x 16n
    float v = red[0][ol][nl] + red[1][ol][nl] + red[2][ol][nl] + red[3][ol][nl];
    int o = ob + ol, nr = n0 + nl;
    out[(size_t)nr * OUT_CH + o] = v + R[(size_t)nr * OUT_CH + o] + bias[o];
}

// ---------------------------------------------------------------------------
// Kernel C (heavy, runs LAST): out[n,:] += e_compress[n,:]
//   G[b] = sum_m adj[n,m]*relu(sum_e ea[e,n,m]*L1[e,b]);  e_comp = G[:127]@L2
// One block (4 waves) per n. Wave owns 256 m = 8 chunks of 32 m.
// Chunks staged via global_load_lds DMA into per-wave double-buffered LDS
// tiles [32e][32m], 2-deep prefetch, explicit s_waitcnt vmcnt(4) so chunk c
// is resident while chunk c+1 streams. No big register arrays -> no spill.
// ---------------------------------------------------------------------------
__global__ void __launch_bounds__(256, 4)
edge_out_kernel(const float* __restrict__ edge_adj,
                const float* __restrict__ adj,
                const float* __restrict__ L1,
                const float* __restrict__ L2,
                float* __restrict__ out) {
    __shared__ float ea_lds[4][2][EDGE_CH * 32];   // 32 KB: per-wave dbuf tiles
    __shared__ float adj_lds[4][256];              // 4 KB: per-wave adj row slice
    __shared__ float gred[4][OUT_CH];
    __shared__ float gs[OUT_CH];
    __shared__ float part[2][OUT_CH];

    int n = blockIdx.x;
    int tid = threadIdx.x;
    int wave = tid >> 6;
    int lane = tid & 63;
    int quad = lane >> 4;
    int col  = lane & 15;

    // constant A fragments: 8 b-tiles of L1^T [b=bt*16+col][e=quad*8+j]
    bf16x8 a_frag[8];
#pragma unroll
    for (int bt = 0; bt < 8; ++bt) {
        int b = bt * 16 + col;
#pragma unroll
        for (int j = 0; j < 8; ++j) {
            int e = quad * 8 + j;
            float v = (b < OUT_CH - 1) ? L1[e * (OUT_CH - 1) + b] : 0.0f;
            a_frag[bt][j] = f2bf(v);
        }
    }

    float g_acc[8][4];
#pragma unroll
    for (int bt = 0; bt < 8; ++bt)
#pragma unroll
        for (int r = 0; r < 4; ++r) g_acc[bt][r] = 0.0f;

    // DMA source pointers: issue i covers e = i*8 + (lane>>3), 16 B at
    // m = wave*256 + (lane&7)*4 (+ chunk*32).
    const float* g0 = edge_adj + (size_t)(lane >> 3) * (size_t)(NN * NN)
                    + (size_t)n * NN + wave * 256 + (lane & 7) * 4;
    float* my_ea = &ea_lds[wave][0][0];

    // prologue: chunk 0, adj slice, chunk 1
#pragma unroll
    for (int i = 0; i < 4; ++i)
        async_copy16(g0 + (size_t)i * 8 * NN * NN, my_ea + i * 256);
    async_copy16(adj + (size_t)n * NN + wave * 256 + lane * 4, &adj_lds[wave][0]);
#pragma unroll
    for (int i = 0; i < 4; ++i)
        async_copy16(g0 + (size_t)i * 8 * NN * NN + 32, my_ea + 1024 + i * 256);

#pragma unroll
    for (int c = 0; c < 8; ++c) {
        // wait: chunk c resident; chunk c+1 (4 newest DMAs) may stay in flight
        if (c < 7) __builtin_amdgcn_s_waitcnt(0xF74);   // vmcnt(4)
        else       __builtin_amdgcn_s_waitcnt(0xF70);   // vmcnt(0)

        const float* eb = &ea_lds[wave][c & 1][0];
#pragma unroll
        for (int s = 0; s < 2; ++s) {
            float adjv = adj_lds[wave][c * 32 + s * 16 + col];
            bf16x8 bf;
#pragma unroll
            for (int j = 0; j < 8; ++j)
                bf[j] = f2bf(eb[(quad * 8 + j) * 32 + s * 16 + col]);
#pragma unroll
            for (int bt = 0; bt < 8; ++bt) {
                f32x4 d = __builtin_amdgcn_mfma_f32_16x16x32_bf16(
                    a_frag[bt], bf, (f32x4){0.f, 0.f, 0.f, 0.f}, 0, 0, 0);
#pragma unroll
                for (int r = 0; r < 4; ++r)
                    g_acc[bt][r] += fmaxf(d[r], 0.0f) * adjv;
            }
        }

        // issue chunk c+2 into the buffer just freed (buf c&1)
        if (c < 6) {
            int nc = c + 2;
            float* dst = &ea_lds[wave][nc & 1][0];
#pragma unroll
            for (int i = 0; i < 4; ++i)
                async_copy16(g0 + (size_t)i * 8 * NN * NN + nc * 32, dst + i * 256);
        }
    }

    // reduce over the 16 column-lanes of each quad
#pragma unroll
    for (int bt = 0; bt < 8; ++bt)
#pragma unroll
        for (int r = 0; r < 4; ++r) {
            float v = g_acc[bt][r];
            v += __shfl_xor(v, 1);
            v += __shfl_xor(v, 2);
            v += __shfl_xor(v, 4);
            v += __shfl_xor(v, 8);
            g_acc[bt][r] = v;
        }

    if (col == 0) {
#pragma unroll
        for (int bt = 0; bt < 8; ++bt)
#pragma unroll
            for (int r = 0; r < 4; ++r)
                gred[wave][bt * 16 + quad * 4 + r] = g_acc[bt][r];
    }
    __syncthreads();
    if (tid < OUT_CH)
        gs[tid] = gred[0][tid] + gred[1][tid] + gred[2][tid] + gred[3][tid];
    __syncthreads();

    // out[n,o] += sum_{b<127} gs[b]*L2[b,o]
    int o = tid & 127;
    int hf = tid >> 7;
    float acc = 0.f;
    int blo = hf * 64, bhi = hf ? 127 : 64;
#pragma unroll 8
    for (int b = blo; b < bhi; ++b)
        acc += gs[b] * L2[b * OUT_CH + o];
    part[hf][o] = acc;
    __syncthreads();
    if (tid < 128)
        out[(size_t)n * OUT_CH + tid] += part[0][tid] + part[1][tid];
}

extern "C" void kernel_launch(void* const* d_in, const int* in_sizes, int n_in,
                              void* d_out, int out_size, void* d_ws, size_t ws_size,
                              hipStream_t stream) {
    const float* node_mat    = (const float*)d_in[0];
    const float* adj         = (const float*)d_in[1];
    const float* edge_adj    = (const float*)d_in[2];
    const float* node_weight = (const float*)d_in[3];
    const float* edge_lay_1  = (const float*)d_in[4];
    const float* edge_lay_2  = (const float*)d_in[5];
    const float* root        = (const float*)d_in[6];
    const float* bias        = (const float*)d_in[7];
    float* out = (float*)d_out;

    short* PT = (short*)d_ws;                                         // 256 KB
    float* R  = (float*)((char*)d_ws + OUT_CH * NN * sizeof(short));  // 512 KB

    node_gemm_kernel<<<NN / 2, 256, 0, stream>>>(node_mat, node_weight, root, PT, R);
    adjp_kernel<<<512, 256, 0, stream>>>(adj, PT, R, bias, out);
    edge_out_kernel<<<NN, 256, 0, stream>>>(edge_adj, adj, edge_lay_1, edge_lay_2, out);
}

// Round 6
// 262.444 us; speedup vs baseline: 1.8289x; 1.8289x over previous
//
#include <hip/hip_runtime.h>
#include <hip/hip_bf16.h>

#define NN 1024
#define IN_CH 128
#define EDGE_CH 32
#define OUT_CH 128

typedef __attribute__((ext_vector_type(8))) short bf16x8;
typedef __attribute__((ext_vector_type(4))) float f32x4;

// round-to-nearest-even float -> bf16
static __device__ __forceinline__ short f2bf(float f) {
    union { float f; unsigned u; } v; v.f = f;
    unsigned r = v.u + 0x7FFFu + ((v.u >> 16) & 1u);
    return (short)(r >> 16);
}

// async global->LDS DMA, 16 B/lane: lane i lands at lptr + i*16 (wave-uniform lptr).
static __device__ __forceinline__ void async_copy16(const float* gptr, float* lptr) {
    __builtin_amdgcn_global_load_lds(
        (const __attribute__((address_space(1))) void*)gptr,
        (__attribute__((address_space(3))) void*)lptr,
        16, 0, 0);
}

// ---------------------------------------------------------------------------
// Kernel A (MFMA): PF[m][o] = node_mat @ node_weight (fp32),
//                  R[m][o]  = node_mat @ root (fp32).
// grid 64 x 256: block = 16 m-rows x all 128 o. Wave w owns o-tiles 2w,2w+1.
// A-frag: A[row=lane&15][k=quad*8+j]; B-frag: B[k][col]; D: row=quad*4+r.
// ---------------------------------------------------------------------------
__global__ void node_gemm_kernel(const float* __restrict__ node_mat,
                                 const float* __restrict__ node_weight,
                                 const float* __restrict__ root,
                                 float* __restrict__ PF,
                                 float* __restrict__ R) {
    int tid = threadIdx.x;
    int wave = tid >> 6, lane = tid & 63, quad = lane >> 4, col = lane & 15;
    int m0 = blockIdx.x * 16;

    f32x4 accP[2] = {{0.f,0.f,0.f,0.f},{0.f,0.f,0.f,0.f}};
    f32x4 accR[2] = {{0.f,0.f,0.f,0.f},{0.f,0.f,0.f,0.f}};

#pragma unroll
    for (int ks = 0; ks < 4; ++ks) {
        bf16x8 a;
#pragma unroll
        for (int j = 0; j < 8; ++j)
            a[j] = f2bf(node_mat[(m0 + col) * IN_CH + ks * 32 + quad * 8 + j]);
#pragma unroll
        for (int t = 0; t < 2; ++t) {
            int ob = (wave * 2 + t) * 16;
            bf16x8 bw, br;
#pragma unroll
            for (int j = 0; j < 8; ++j) {
                int k = ks * 32 + quad * 8 + j;
                bw[j] = f2bf(node_weight[k * OUT_CH + ob + col]);
                br[j] = f2bf(root[k * OUT_CH + ob + col]);
            }
            accP[t] = __builtin_amdgcn_mfma_f32_16x16x32_bf16(a, bw, accP[t], 0, 0, 0);
            accR[t] = __builtin_amdgcn_mfma_f32_16x16x32_bf16(a, br, accR[t], 0, 0, 0);
        }
    }
#pragma unroll
    for (int t = 0; t < 2; ++t)
#pragma unroll
        for (int r = 0; r < 4; ++r) {
            int m = m0 + quad * 4 + r;
            int o = (wave * 2 + t) * 16 + col;
            PF[(size_t)m * OUT_CH + o] = accP[t][r];
            R[(size_t)m * OUT_CH + o]  = accR[t][r];
        }
}

// ---------------------------------------------------------------------------
// Kernel B (fused, heavy): per node n computes the FULL output row:
//   G[b]     = sum_m adj[n,m] * relu( sum_e ea[e,n,m] * L1[e,b] )
//   out[n,o] = sum_b<127 G[b]*L2[b,o] + sum_m adj[n,m]*PF[m,o] + R[n,o] + bias[o]
// One block per n, 4 waves. Wave w owns ONLY b in [32w,32w+32): a_frag[2] +
// g_acc[2][4] -> ~40 VGPR total, no spill (R2/R4/R5 failure mode was the
// 8-tile/wave working set eating the whole 64-VGPR budget).
// ea staged per 64-m chunk via global_load_lds into double-buffered LDS
// (8 issues/chunk, 2 per wave), 16-B pad between issues (260-float stride)
// -> ds_reads are 2-way (free) while DMA stays contiguous per issue.
// ---------------------------------------------------------------------------
__global__ void __launch_bounds__(256)
fused_kernel(const float* __restrict__ edge_adj,
             const float* __restrict__ adj,
             const float* __restrict__ L1,
             const float* __restrict__ L2,
             const float* __restrict__ PF,
             const float* __restrict__ R,
             const float* __restrict__ bias,
             float* __restrict__ out) {
    __shared__ float ea_lds[2][8 * 260];   // 2 x 8.3 KB, dbuf; issue i at i*260
    __shared__ float adj_lds[NN];          // full adj row, 4 KB
    __shared__ float gs[OUT_CH];
    __shared__ float part[2][OUT_CH];

    int n = blockIdx.x;
    int tid = threadIdx.x;
    int wave = tid >> 6, lane = tid & 63, quad = lane >> 4, col = lane & 15;

    // A-frags for this wave's 2 b-tiles: b = wave*32 + t*16 + col
    bf16x8 a_frag[2];
#pragma unroll
    for (int t = 0; t < 2; ++t) {
        int b = wave * 32 + t * 16 + col;
#pragma unroll
        for (int j = 0; j < 8; ++j) {
            int e = quad * 8 + j;
            a_frag[t][j] = (b < OUT_CH - 1) ? f2bf(L1[e * (OUT_CH - 1) + b]) : (short)0;
        }
    }
    float g_acc[2][4] = {{0.f,0.f,0.f,0.f},{0.f,0.f,0.f,0.f}};

    // DMA geometry: issue q of this wave covers e-rows (2*wave+q)*4 .. +3.
    // lane i: e = (2w+q)*4 + (i>>4), m = chunk*64 + (i&15)*4; 16 B each.
    const float* gsrc = edge_adj + (size_t)n * NN;
    size_t eoff0 = ((size_t)(2 * wave + 0) * 4 + (lane >> 4)) * (size_t)(NN * NN)
                 + (size_t)((lane & 15) * 4);
    size_t eoff1 = ((size_t)(2 * wave + 1) * 4 + (lane >> 4)) * (size_t)(NN * NN)
                 + (size_t)((lane & 15) * 4);
    float* dst0 = &ea_lds[0][(2 * wave + 0) * 260];
    float* dst1 = &ea_lds[0][(2 * wave + 1) * 260];
    float* dst0b = &ea_lds[1][(2 * wave + 0) * 260];
    float* dst1b = &ea_lds[1][(2 * wave + 1) * 260];

    // prologue: chunk 0 -> buf0, adj row (1 issue/wave), chunk 1 -> buf1
    async_copy16(gsrc + eoff0, dst0);
    async_copy16(gsrc + eoff1, dst1);
    async_copy16(adj + (size_t)n * NN + wave * 256 + lane * 4, &adj_lds[wave * 256]);
    async_copy16(gsrc + eoff0 + 64, dst0b);
    async_copy16(gsrc + eoff1 + 64, dst1b);

    for (int c = 0; c < 16; ++c) {
        // drain this wave's chunk-c DMAs (chunk c+1's 2 stay in flight)
        if (c < 15) __builtin_amdgcn_s_waitcnt(0xF72);   // vmcnt(2)
        else        __builtin_amdgcn_s_waitcnt(0xF70);   // vmcnt(0)
        __syncthreads();   // all waves' chunk-c (and adj) data resident

        const float* eb = ea_lds[c & 1];
#pragma unroll
        for (int s = 0; s < 4; ++s) {
            float adjv = adj_lds[c * 64 + s * 16 + col];
            bf16x8 bf;
#pragma unroll
            for (int j = 0; j < 8; ++j) {
                int e = quad * 8 + j;
                bf[j] = f2bf(eb[(e >> 2) * 260 + (e & 3) * 64 + s * 16 + col]);
            }
#pragma unroll
            for (int t = 0; t < 2; ++t) {
                f32x4 d = __builtin_amdgcn_mfma_f32_16x16x32_bf16(
                    a_frag[t], bf, (f32x4){0.f, 0.f, 0.f, 0.f}, 0, 0, 0);
#pragma unroll
                for (int r = 0; r < 4; ++r)
                    g_acc[t][r] += fmaxf(d[r], 0.0f) * adjv;
            }
        }
        __syncthreads();   // everyone done reading buf c&1

        // refill the just-freed buffer with chunk c+2
        if (c < 14) {
            int nc = c + 2;
            float* d0 = &ea_lds[nc & 1][(2 * wave + 0) * 260];
            float* d1 = &ea_lds[nc & 1][(2 * wave + 1) * 260];
            async_copy16(gsrc + eoff0 + nc * 64, d0);
            async_copy16(gsrc + eoff1 + nc * 64, d1);
        }
    }

    // reduce over the 16 m-lanes (col); col==0 holds G[b], b = wave*32+t*16+quad*4+r
#pragma unroll
    for (int t = 0; t < 2; ++t)
#pragma unroll
        for (int r = 0; r < 4; ++r) {
            float v = g_acc[t][r];
            v += __shfl_xor(v, 1);
            v += __shfl_xor(v, 2);
            v += __shfl_xor(v, 4);
            v += __shfl_xor(v, 8);
            if (col == 0) gs[wave * 32 + t * 16 + quad * 4 + r] = v;
        }
    __syncthreads();

    // epilogue: e_compress + adj@P, split m/b across the two thread-halves
    int o = tid & 127;
    int hf = tid >> 7;
    float acc = 0.f;
    int blo = hf * 64, bhi = hf ? (OUT_CH - 1) : 64;
#pragma unroll 8
    for (int b = blo; b < bhi; ++b)
        acc += gs[b] * L2[b * OUT_CH + o];

    // adj @ P over this half's 512 m (PF is 512 KB fp32, L2-resident)
    float a0 = 0.f, a1 = 0.f, a2 = 0.f, a3 = 0.f;
    const float* pf = PF + (size_t)(hf * 512) * OUT_CH + o;
    const float* aw = &adj_lds[hf * 512];
    for (int mm = 0; mm < 512; mm += 4) {
        a0 += aw[mm + 0] * pf[(size_t)(mm + 0) * OUT_CH];
        a1 += aw[mm + 1] * pf[(size_t)(mm + 1) * OUT_CH];
        a2 += aw[mm + 2] * pf[(size_t)(mm + 2) * OUT_CH];
        a3 += aw[mm + 3] * pf[(size_t)(mm + 3) * OUT_CH];
    }
    acc += (a0 + a1) + (a2 + a3);
    part[hf][o] = acc;
    __syncthreads();
    if (tid < 128)
        out[(size_t)n * OUT_CH + tid] =
            part[0][tid] + part[1][tid] + R[(size_t)n * OUT_CH + tid] + bias[tid];
}

extern "C" void kernel_launch(void* const* d_in, const int* in_sizes, int n_in,
                              void* d_out, int out_size, void* d_ws, size_t ws_size,
                              hipStream_t stream) {
    const float* node_mat    = (const float*)d_in[0];
    const float* adj         = (const float*)d_in[1];
    const float* edge_adj    = (const float*)d_in[2];
    const float* node_weight = (const float*)d_in[3];
    const float* edge_lay_1  = (const float*)d_in[4];
    const float* edge_lay_2  = (const float*)d_in[5];
    const float* root        = (const float*)d_in[6];
    const float* bias        = (const float*)d_in[7];
    float* out = (float*)d_out;

    float* PF = (float*)d_ws;                 // 1024*128 fp32 = 512 KB
    float* R  = PF + NN * OUT_CH;             // 512 KB

    node_gemm_kernel<<<64, 256, 0, stream>>>(node_mat, node_weight, root, PF, R);
    fused_kernel<<<NN, 256, 0, stream>>>(edge_adj, adj, edge_lay_1, edge_lay_2,
                                         PF, R, bias, out);
}